// Round 5
// baseline (1911.512 us; speedup 1.0000x reference)
//
#include <hip/hip_runtime.h>
#include <hip/hip_bf16.h>

// TimeLSTM fused persistent kernel for MI355X (gfx950), v5.
// B=2048, T=512, D=24, H=100, O=2. 512 blocks x 4 batch rows (2 blocks/CU),
// 512 threads. A-fragment packs h AND c with duplicates:
//   rows 0-3 = [h|x|1], rows 4-7 = [c|0|1], rows 8-11 = c copy, rows 12-15 = h copy.
// One tile-set of 5 B-tiles {f,i,o,c~,decay} per wave (j-group = wave*16..+16):
//   gate tiles valid on rows 0-3 & 12-15; decay tile valid on rows 4-11.
// Quintet redistribution needs only shfl_xor(32): lane group G handles row
// r(G) = {G0:0, G2:1, G1:2, G3:3}; 1 cell/lane. One barrier/step.
// Wave 7 stages x[s+1] (rows 0-3 and 12-15) + ts[s+1].

typedef __attribute__((ext_vector_type(8))) short bf16x8;
typedef __attribute__((ext_vector_type(4))) float f32x4;

#define B_SZ 2048
#define T_SZ 512
#define D_SZ 24
#define H_SZ 100
#define O_SZ 2
#define RPB 4            // batch rows per block

__device__ __forceinline__ unsigned short f2bf(float v) {
    return __builtin_bit_cast(unsigned short, __float2bfloat16(v));
}
__device__ __forceinline__ float fexp2(float x) { return __builtin_amdgcn_exp2f(x); }
__device__ __forceinline__ float frcp (float x) { return __builtin_amdgcn_rcpf(x); }
__device__ __forceinline__ float sigm(float x) { return frcp(1.0f + fexp2(-1.44269504f * x)); }
__device__ __forceinline__ float tanh_(float x) {
    return __builtin_fmaf(-2.0f, frcp(1.0f + fexp2(2.88539008f * x)), 1.0f);
}

__global__ __launch_bounds__(512, 4) void tlstm_kernel(
    const float* __restrict__ input_seq, const float* __restrict__ ts,
    const float* __restrict__ W_all, const float* __restrict__ b_all,
    const float* __restrict__ U_all, const float* __restrict__ b_u,
    const float* __restrict__ W_d,  const float* __restrict__ b_d,
    const float* __restrict__ W_lin, const float* __restrict__ b_lin,
    float* __restrict__ out)
{
    // hx: [parity][16 rows][128 k-slots] bf16, XOR-swizzled per row:
    //   idx = r*128 + (k ^ ((r&7)<<3)).  Slots: 0..99 h/c, 100..123 x (h-rows
    //   only), 124 = 1.0 bias (all rows), 125..127 = 0.
    __shared__ unsigned short hx[2][16 * 128];
    __shared__ float ts_lds[2][RPB];
    __shared__ float hl[RPB][H_SZ];

    const int tid   = (int)threadIdx.x;
    const int lane  = tid & 63;
    const int wave  = tid >> 6;
    const int row16 = lane & 15;
    const int kgrp  = lane >> 4;
    const int G     = lane >> 4;          // 16-lane group id
    const int rowbase = (int)blockIdx.x * RPB;

    // ---- init both parities: zeros + bias slot (k=124) = 1.0 on ALL rows ----
    for (int i = tid; i < 2 * 16 * 128; i += 512) {
        const int p = i >> 11, r = (i >> 7) & 15, k = i & 127;
        const unsigned short v = (k == 124) ? (unsigned short)0x3F80 : (unsigned short)0;
        hx[p][r * 128 + (k ^ ((r & 7) << 3))] = v;
    }

    // ---- stationary B fragments: wave w<7 -> j in [16w,16w+16), 5 tiles ----
    const int jj = wave * 16 + row16;
    bf16x8 Bf[5][4];
    #pragma unroll
    for (int t = 0; t < 5; ++t) {
        #pragma unroll
        for (int g = 0; g < 4; ++g) {
            bf16x8 fr;
            #pragma unroll
            for (int e = 0; e < 8; ++e) {
                const int k = g * 32 + kgrp * 8 + e;
                float v = 0.0f;
                if (jj < H_SZ) {
                    if (t < 4) {
                        const int n = t * H_SZ + jj;
                        if (k < 100)       v = W_all[k * 400 + n];
                        else if (k < 124)  v = U_all[(k - 100) * 400 + n];
                        else if (k == 124) v = b_all[n] + b_u[n];
                    } else {
                        if (k < 100)       v = W_d[k * 100 + jj];
                        else if (k == 124) v = b_d[jj];
                    }
                }
                fr[e] = (short)f2bf(v);
            }
            Bf[t][g] = fr;
        }
    }

    __syncthreads();   // init visible before staging overwrites x slots

    // ---- stage x[0] (rows 0-3 and 12-15) and ts[0] into parity 0 ----
    if (wave == 7) {
        #pragma unroll
        for (int q = 0; q < 3; ++q) {
            const int ii = lane * 3 + q;           // 0..191 (96 values x 2 rows)
            const int r8 = ii / 24, d = ii % 24;
            const int tr = (r8 < 4) ? r8 : 8 + r8; // 0-3 and 12-15
            const float v = input_seq[((size_t)(rowbase + (r8 & 3)) * T_SZ + 0) * D_SZ + d];
            hx[0][tr * 128 + ((100 + d) ^ ((tr & 7) << 3))] = f2bf(v);
        }
        if (lane < RPB) ts_lds[0][lane] = ts[(size_t)(rowbase + lane) * T_SZ + 0];
    }

    // per-lane cell assignment: r by group {G0:0, G1:2, G2:1, G3:3}
    const int r = (G == 0) ? 0 : (G == 1) ? 2 : (G == 2) ? 1 : 3;
    const bool epi = (wave < 7) && (jj < H_SZ);
    // hoisted publish addresses (h -> rows r, 12+r ; c -> rows 4+r, 8+r)
    const int ixh0 = (r     ) * 128 + (jj ^ (((r     ) & 7) << 3));
    const int ixh1 = (12 + r) * 128 + (jj ^ (((12 + r) & 7) << 3));
    const int ixc0 = (4 + r ) * 128 + (jj ^ (((4 + r ) & 7) << 3));
    const int ixc1 = (8 + r ) * 128 + (jj ^ (((8 + r ) & 7) << 3));
    float cst = 0.f;                       // f32 cell-state carry (1 cell/lane)

    __syncthreads();

    int par = 0;
    for (int s = 0; s < T_SZ; ++s) {
        const unsigned short* hp = hx[par];

        if (wave < 7) {
            // single A-fragment (covers h, c, and copies) : 4 ds_read_b128
            bf16x8 a4[4];
            #pragma unroll
            for (int g = 0; g < 4; ++g) {
                const int idx = row16 * 128 + ((g * 32 + kgrp * 8) ^ ((row16 & 7) << 3));
                a4[g] = *(const bf16x8*)(hp + idx);
            }

            f32x4 acc[5];
            #pragma unroll
            for (int t = 0; t < 5; ++t) {
                f32x4 a = {0.f, 0.f, 0.f, 0.f};
                #pragma unroll
                for (int g = 0; g < 4; ++g)
                    a = __builtin_amdgcn_mfma_f32_16x16x32_bf16(a4[g], Bf[t][g], a, 0, 0, 0);
                acc[t] = a;
            }

            // cross-half exchange (xor 32 only):
            //   gates elem1 -> G2, elem2 -> G1 ; decay elem0 -> G0, elem3 -> G3
            float swg1[4], swg2[4];
            #pragma unroll
            for (int t = 0; t < 4; ++t) {
                swg1[t] = __shfl_xor(acc[t][1], 32, 64);
                swg2[t] = __shfl_xor(acc[t][2], 32, 64);
            }
            const float swd0 = __shfl_xor(acc[4][0], 32, 64);
            const float swd3 = __shfl_xor(acc[4][3], 32, 64);

            if (epi) {
                unsigned short* hn = hx[par ^ 1];
                float gg[4];
                #pragma unroll
                for (int t = 0; t < 4; ++t)
                    gg[t] = (G == 0) ? acc[t][0] : (G == 1) ? swg2[t]
                          : (G == 2) ? swg1[t]   : acc[t][3];
                const float dd = (G == 0) ? swd0 : (G == 1) ? acc[4][2]
                               : (G == 2) ? acc[4][1] : swd3;

                const float tsv = ts_lds[par][r];
                const float f = sigm(gg[0]);
                const float i = sigm(gg[1]);
                const float o = sigm(gg[2]);
                const float g = sigm(gg[3]);
                const float cs = tanh_(dd);
                const float ca = cst + cs * (tsv - 1.0f);   // (c - cs) + cs*t
                cst = f * ca + i * g;
                const float h = o * tanh_(cst);

                const unsigned short hb = f2bf(h);
                const unsigned short cb = f2bf(cst);
                hn[ixh0] = hb;  hn[ixh1] = hb;
                hn[ixc0] = cb;  hn[ixc1] = cb;
                if (s == T_SZ - 1) hl[r][jj] = h;
            }
        } else {
            // staging wave: x[s+1] into rows 0-3 & 12-15, ts[s+1] (other parity)
            const int s1 = (s + 1 < T_SZ) ? (s + 1) : s;
            #pragma unroll
            for (int q = 0; q < 3; ++q) {
                const int ii = lane * 3 + q;
                const int r8 = ii / 24, d = ii % 24;
                const int tr = (r8 < 4) ? r8 : 8 + r8;
                const float v = input_seq[((size_t)(rowbase + (r8 & 3)) * T_SZ + s1) * D_SZ + d];
                hx[par ^ 1][tr * 128 + ((100 + d) ^ ((tr & 7) << 3))] = f2bf(v);
            }
            if (lane < RPB) ts_lds[par ^ 1][lane] = ts[(size_t)(rowbase + lane) * T_SZ + s1];
        }

        __syncthreads();   // single barrier per step (double-buffered state)
        par ^= 1;
    }

    // ---- output head: relu(h_last @ W_lin + b_lin), parallel reduce ----
    if (tid < 64 * RPB) {
        const int rr = tid >> 6;        // 0..3 (one wave per row)
        const int o  = (tid >> 5) & 1;  // half-wave per output col
        const int k0 = tid & 31;
        float part = 0.f;
        for (int k = k0; k < H_SZ; k += 32)
            part += hl[rr][k] * W_lin[k * O_SZ + o];
        #pragma unroll
        for (int off = 16; off; off >>= 1)
            part += __shfl_xor(part, off, 64);
        if (k0 == 0)
            out[(size_t)(rowbase + rr) * O_SZ + o] = fmaxf(part + b_lin[o], 0.f);
    }
}

extern "C" void kernel_launch(void* const* d_in, const int* in_sizes, int n_in,
                              void* d_out, int out_size, void* d_ws, size_t ws_size,
                              hipStream_t stream) {
    const float* input_seq = (const float*)d_in[0];
    const float* ts_p      = (const float*)d_in[1];
    const float* W_all     = (const float*)d_in[2];
    const float* b_all     = (const float*)d_in[3];
    const float* U_all     = (const float*)d_in[4];
    const float* b_u       = (const float*)d_in[5];
    const float* W_d       = (const float*)d_in[6];
    const float* b_d       = (const float*)d_in[7];
    const float* W_lin     = (const float*)d_in[8];
    const float* b_lin     = (const float*)d_in[9];

    tlstm_kernel<<<dim3(B_SZ / RPB), dim3(512), 0, stream>>>(
        input_seq, ts_p, W_all, b_all, U_all, b_u, W_d, b_d, W_lin, b_lin,
        (float*)d_out);
}

// Round 6
// 1326.504 us; speedup vs baseline: 1.4410x; 1.4410x over previous
//
#include <hip/hip_runtime.h>
#include <hip/hip_bf16.h>

// TimeLSTM fused persistent kernel for MI355X (gfx950), v6.
// B=2048, T=512, D=24, H=100, O=2. 512 blocks x 4 batch rows, 512 threads.
// Intended residency: 2 blocks/CU (kernel uses ~108 VGPR <= 128 -> 4 waves/SIMD).
// v5's (512,4) launch-bounds capped VGPR at 64 and spilled the 80-VGPR
// stationary weight fragments to scratch (88MB HBM writes/step-loop) -> 3.4x
// regression. v6 = identical algorithm with the v4 register budget (512,2).
// A-fragment packs h AND c with duplicates:
//   rows 0-3 = [h|x|1], rows 4-7 = [c|0|1], rows 8-11 = c copy, rows 12-15 = h copy.
// Wave w<7 owns j-columns [16w,16w+16) with 5 B-tiles {f,i,o,c~,decay};
// lane group G handles row r(G) = {G0:0, G2:1, G1:2, G3:3}; 1 cell/lane;
// only shfl_xor(32) cross-half exchange. One barrier/step. Wave 7 stages
// x[s+1]/ts[s+1] into the next parity buffer.

typedef __attribute__((ext_vector_type(8))) short bf16x8;
typedef __attribute__((ext_vector_type(4))) float f32x4;

#define B_SZ 2048
#define T_SZ 512
#define D_SZ 24
#define H_SZ 100
#define O_SZ 2
#define RPB 4            // batch rows per block

__device__ __forceinline__ unsigned short f2bf(float v) {
    return __builtin_bit_cast(unsigned short, __float2bfloat16(v));
}
__device__ __forceinline__ float fexp2(float x) { return __builtin_amdgcn_exp2f(x); }
__device__ __forceinline__ float frcp (float x) { return __builtin_amdgcn_rcpf(x); }
__device__ __forceinline__ float sigm(float x) { return frcp(1.0f + fexp2(-1.44269504f * x)); }
__device__ __forceinline__ float tanh_(float x) {
    return __builtin_fmaf(-2.0f, frcp(1.0f + fexp2(2.88539008f * x)), 1.0f);
}

__global__ __launch_bounds__(512, 2) void tlstm_kernel(
    const float* __restrict__ input_seq, const float* __restrict__ ts,
    const float* __restrict__ W_all, const float* __restrict__ b_all,
    const float* __restrict__ U_all, const float* __restrict__ b_u,
    const float* __restrict__ W_d,  const float* __restrict__ b_d,
    const float* __restrict__ W_lin, const float* __restrict__ b_lin,
    float* __restrict__ out)
{
    // hx: [parity][16 rows][128 k-slots] bf16, XOR-swizzled per row:
    //   idx = r*128 + (k ^ ((r&7)<<3)).  Slots: 0..99 h/c, 100..123 x (h-rows
    //   only), 124 = 1.0 bias (all rows), 125..127 = 0.
    __shared__ unsigned short hx[2][16 * 128];
    __shared__ float ts_lds[2][RPB];
    __shared__ float hl[RPB][H_SZ];

    const int tid   = (int)threadIdx.x;
    const int lane  = tid & 63;
    const int wave  = tid >> 6;
    const int row16 = lane & 15;
    const int kgrp  = lane >> 4;
    const int G     = lane >> 4;          // 16-lane group id
    const int rowbase = (int)blockIdx.x * RPB;

    // ---- init both parities: zeros + bias slot (k=124) = 1.0 on ALL rows ----
    for (int i = tid; i < 2 * 16 * 128; i += 512) {
        const int p = i >> 11, r = (i >> 7) & 15, k = i & 127;
        const unsigned short v = (k == 124) ? (unsigned short)0x3F80 : (unsigned short)0;
        hx[p][r * 128 + (k ^ ((r & 7) << 3))] = v;
    }

    // ---- stationary B fragments: wave w<7 -> j in [16w,16w+16), 5 tiles ----
    const int jj = wave * 16 + row16;
    bf16x8 Bf[5][4];
    #pragma unroll
    for (int t = 0; t < 5; ++t) {
        #pragma unroll
        for (int g = 0; g < 4; ++g) {
            bf16x8 fr;
            #pragma unroll
            for (int e = 0; e < 8; ++e) {
                const int k = g * 32 + kgrp * 8 + e;
                float v = 0.0f;
                if (jj < H_SZ) {
                    if (t < 4) {
                        const int n = t * H_SZ + jj;
                        if (k < 100)       v = W_all[k * 400 + n];
                        else if (k < 124)  v = U_all[(k - 100) * 400 + n];
                        else if (k == 124) v = b_all[n] + b_u[n];
                    } else {
                        if (k < 100)       v = W_d[k * 100 + jj];
                        else if (k == 124) v = b_d[jj];
                    }
                }
                fr[e] = (short)f2bf(v);
            }
            Bf[t][g] = fr;
        }
    }

    __syncthreads();   // init visible before staging overwrites x slots

    // ---- stage x[0] (rows 0-3 and 12-15) and ts[0] into parity 0 ----
    if (wave == 7) {
        #pragma unroll
        for (int q = 0; q < 3; ++q) {
            const int ii = lane * 3 + q;           // 0..191 (96 values x 2 rows)
            const int r8 = ii / 24, d = ii % 24;
            const int tr = (r8 < 4) ? r8 : 8 + r8; // 0-3 and 12-15
            const float v = input_seq[((size_t)(rowbase + (r8 & 3)) * T_SZ + 0) * D_SZ + d];
            hx[0][tr * 128 + ((100 + d) ^ ((tr & 7) << 3))] = f2bf(v);
        }
        if (lane < RPB) ts_lds[0][lane] = ts[(size_t)(rowbase + lane) * T_SZ + 0];
    }

    // per-lane cell assignment: r by group {G0:0, G1:2, G2:1, G3:3}
    const int r = (G == 0) ? 0 : (G == 1) ? 2 : (G == 2) ? 1 : 3;
    const bool epi = (wave < 7) && (jj < H_SZ);
    // hoisted publish addresses (h -> rows r, 12+r ; c -> rows 4+r, 8+r)
    const int ixh0 = (r     ) * 128 + (jj ^ (((r     ) & 7) << 3));
    const int ixh1 = (12 + r) * 128 + (jj ^ (((12 + r) & 7) << 3));
    const int ixc0 = (4 + r ) * 128 + (jj ^ (((4 + r ) & 7) << 3));
    const int ixc1 = (8 + r ) * 128 + (jj ^ (((8 + r ) & 7) << 3));
    float cst = 0.f;                       // f32 cell-state carry (1 cell/lane)

    __syncthreads();

    int par = 0;
    for (int s = 0; s < T_SZ; ++s) {
        const unsigned short* hp = hx[par];

        if (wave < 7) {
            // single A-fragment (covers h, c, and copies) : 4 ds_read_b128
            bf16x8 a4[4];
            #pragma unroll
            for (int g = 0; g < 4; ++g) {
                const int idx = row16 * 128 + ((g * 32 + kgrp * 8) ^ ((row16 & 7) << 3));
                a4[g] = *(const bf16x8*)(hp + idx);
            }

            f32x4 acc[5];
            #pragma unroll
            for (int t = 0; t < 5; ++t) {
                f32x4 a = {0.f, 0.f, 0.f, 0.f};
                #pragma unroll
                for (int g = 0; g < 4; ++g)
                    a = __builtin_amdgcn_mfma_f32_16x16x32_bf16(a4[g], Bf[t][g], a, 0, 0, 0);
                acc[t] = a;
            }

            // cross-half exchange (xor 32 only):
            //   gates elem1 -> G2, elem2 -> G1 ; decay elem0 -> G0, elem3 -> G3
            float swg1[4], swg2[4];
            #pragma unroll
            for (int t = 0; t < 4; ++t) {
                swg1[t] = __shfl_xor(acc[t][1], 32, 64);
                swg2[t] = __shfl_xor(acc[t][2], 32, 64);
            }
            const float swd0 = __shfl_xor(acc[4][0], 32, 64);
            const float swd3 = __shfl_xor(acc[4][3], 32, 64);

            if (epi) {
                unsigned short* hn = hx[par ^ 1];
                float gg[4];
                #pragma unroll
                for (int t = 0; t < 4; ++t)
                    gg[t] = (G == 0) ? acc[t][0] : (G == 1) ? swg2[t]
                          : (G == 2) ? swg1[t]   : acc[t][3];
                const float dd = (G == 0) ? swd0 : (G == 1) ? acc[4][2]
                               : (G == 2) ? acc[4][1] : swd3;

                const float tsv = ts_lds[par][r];
                const float f = sigm(gg[0]);
                const float i = sigm(gg[1]);
                const float o = sigm(gg[2]);
                const float g = sigm(gg[3]);
                const float cs = tanh_(dd);
                const float ca = cst + cs * (tsv - 1.0f);   // (c - cs) + cs*t
                cst = f * ca + i * g;
                const float h = o * tanh_(cst);

                const unsigned short hb = f2bf(h);
                const unsigned short cb = f2bf(cst);
                hn[ixh0] = hb;  hn[ixh1] = hb;
                hn[ixc0] = cb;  hn[ixc1] = cb;
                if (s == T_SZ - 1) hl[r][jj] = h;
            }
        } else {
            // staging wave: x[s+1] into rows 0-3 & 12-15, ts[s+1] (other parity)
            const int s1 = (s + 1 < T_SZ) ? (s + 1) : s;
            #pragma unroll
            for (int q = 0; q < 3; ++q) {
                const int ii = lane * 3 + q;
                const int r8 = ii / 24, d = ii % 24;
                const int tr = (r8 < 4) ? r8 : 8 + r8;
                const float v = input_seq[((size_t)(rowbase + (r8 & 3)) * T_SZ + s1) * D_SZ + d];
                hx[par ^ 1][tr * 128 + ((100 + d) ^ ((tr & 7) << 3))] = f2bf(v);
            }
            if (lane < RPB) ts_lds[par ^ 1][lane] = ts[(size_t)(rowbase + lane) * T_SZ + s1];
        }

        __syncthreads();   // single barrier per step (double-buffered state)
        par ^= 1;
    }

    // ---- output head: relu(h_last @ W_lin + b_lin), parallel reduce ----
    if (tid < 64 * RPB) {
        const int rr = tid >> 6;        // 0..3 (one wave per row)
        const int o  = (tid >> 5) & 1;  // half-wave per output col
        const int k0 = tid & 31;
        float part = 0.f;
        for (int k = k0; k < H_SZ; k += 32)
            part += hl[rr][k] * W_lin[k * O_SZ + o];
        #pragma unroll
        for (int off = 16; off; off >>= 1)
            part += __shfl_xor(part, off, 64);
        if (k0 == 0)
            out[(size_t)(rowbase + rr) * O_SZ + o] = fmaxf(part + b_lin[o], 0.f);
    }
}

extern "C" void kernel_launch(void* const* d_in, const int* in_sizes, int n_in,
                              void* d_out, int out_size, void* d_ws, size_t ws_size,
                              hipStream_t stream) {
    const float* input_seq = (const float*)d_in[0];
    const float* ts_p      = (const float*)d_in[1];
    const float* W_all     = (const float*)d_in[2];
    const float* b_all     = (const float*)d_in[3];
    const float* U_all     = (const float*)d_in[4];
    const float* b_u       = (const float*)d_in[5];
    const float* W_d       = (const float*)d_in[6];
    const float* b_d       = (const float*)d_in[7];
    const float* W_lin     = (const float*)d_in[8];
    const float* b_lin     = (const float*)d_in[9];

    tlstm_kernel<<<dim3(B_SZ / RPB), dim3(512), 0, stream>>>(
        input_seq, ts_p, W_all, b_all, U_all, b_u, W_d, b_d, W_lin, b_lin,
        (float*)d_out);
}

// Round 10
// 592.040 us; speedup vs baseline: 3.2287x; 2.2406x over previous
//
#include <hip/hip_runtime.h>
#include <hip/hip_bf16.h>

// TimeLSTM fused persistent kernel for MI355X (gfx950), v7 (3rd resubmit;
// R7/R9 GPU-acquisition timeouts, R8 container failure — kernel has never
// run on hardware).
// B=2048, T=512, D=24, H=100, O=2. 256 blocks x 8 batch rows, 512 threads.
// v4 shape (best: 550us) with packed A-fragment -- NO row duplication:
//   rows 0-7  = [h | x | 1 | 0]   (real batch rows)
//   rows 8-15 = [c | 0 | 1 | 0]   (same batch rows' cell state)
// Gate tiles (f,i,o,c~) valid on output rows 0-7 (lanes 0-31); decay tile
// valid on rows 8-15 (lanes 32-63); other halves are discarded garbage.
// Halves A-frag ds_reads vs v4 (4 instead of 8) at v4's MFMA count (20/wave).
// Exchange: 10 shfl_xor(32) (8 gate preacts up, 2 decay preacts down), then
// each lane owns 2 cells. One barrier/step. Wave 7 stages x[s+1]/ts[s+1].

typedef __attribute__((ext_vector_type(8))) short bf16x8;
typedef __attribute__((ext_vector_type(4))) float f32x4;

#define B_SZ 2048
#define T_SZ 512
#define D_SZ 24
#define H_SZ 100
#define O_SZ 2
#define RPB 8            // batch rows per block

__device__ __forceinline__ unsigned short f2bf(float v) {
    return __builtin_bit_cast(unsigned short, __float2bfloat16(v));
}
__device__ __forceinline__ float fexp2(float x) { return __builtin_amdgcn_exp2f(x); }
__device__ __forceinline__ float frcp (float x) { return __builtin_amdgcn_rcpf(x); }
__device__ __forceinline__ float sigm(float x) { return frcp(1.0f + fexp2(-1.44269504f * x)); }
__device__ __forceinline__ float tanh_(float x) {
    return __builtin_fmaf(-2.0f, frcp(1.0f + fexp2(2.88539008f * x)), 1.0f);
}

__global__ __launch_bounds__(512, 2) void tlstm_kernel(
    const float* __restrict__ input_seq, const float* __restrict__ ts,
    const float* __restrict__ W_all, const float* __restrict__ b_all,
    const float* __restrict__ U_all, const float* __restrict__ b_u,
    const float* __restrict__ W_d,  const float* __restrict__ b_d,
    const float* __restrict__ W_lin, const float* __restrict__ b_lin,
    float* __restrict__ out)
{
    // hx: [parity][16 rows][128 k-slots] bf16, XOR-swizzled per row:
    //   idx = r*128 + (k ^ ((r&7)<<3)).
    //   rows 0-7:  slots 0..99 = h, 100..123 = x_t, 124 = 1.0, 125..127 = 0
    //   rows 8-15: slots 0..99 = c, 100..123 = 0,   124 = 1.0, 125..127 = 0
    __shared__ unsigned short hx[2][16 * 128];
    __shared__ float ts_lds[2][RPB];
    __shared__ float hl[RPB][H_SZ];

    const int tid   = (int)threadIdx.x;
    const int lane  = tid & 63;
    const int wave  = tid >> 6;
    const int row16 = lane & 15;
    const int kgrp  = lane >> 4;
    const int rowbase = (int)blockIdx.x * RPB;

    // ---- init both parities: zeros + bias slot (k=124) = 1.0 on ALL rows ----
    for (int i = tid; i < 2 * 16 * 128; i += 512) {
        const int p = i >> 11, r = (i >> 7) & 15, k = i & 127;
        const unsigned short v = (k == 124) ? (unsigned short)0x3F80 : (unsigned short)0;
        hx[p][r * 128 + (k ^ ((r & 7) << 3))] = v;
    }

    // ---- stationary B fragments: wave w<7 -> j in [16w,16w+16), 5 tiles ----
    // tile t<4: gate chunk t; tile 4: decay.
    const int jj = wave * 16 + row16;
    bf16x8 Bf[5][4];
    #pragma unroll
    for (int t = 0; t < 5; ++t) {
        #pragma unroll
        for (int g = 0; g < 4; ++g) {
            bf16x8 fr;
            #pragma unroll
            for (int e = 0; e < 8; ++e) {
                const int k = g * 32 + kgrp * 8 + e;
                float v = 0.0f;
                if (jj < H_SZ) {
                    if (t < 4) {
                        const int n = t * H_SZ + jj;
                        if (k < 100)       v = W_all[k * 400 + n];
                        else if (k < 124)  v = U_all[(k - 100) * 400 + n];
                        else if (k == 124) v = b_all[n] + b_u[n];
                    } else {
                        if (k < 100)       v = W_d[k * 100 + jj];
                        else if (k == 124) v = b_d[jj];
                    }
                }
                fr[e] = (short)f2bf(v);
            }
            Bf[t][g] = fr;
        }
    }

    __syncthreads();   // init visible before staging overwrites x slots

    // ---- stage x[0] (rows 0-7) and ts[0] into parity 0 ----
    if (wave == 7) {
        #pragma unroll
        for (int q = 0; q < 3; ++q) {
            const int ii = lane * 3 + q;            // 0..191
            const int r = ii / 24, d = ii % 24;
            const float v = input_seq[((size_t)(rowbase + r) * T_SZ + 0) * D_SZ + d];
            hx[0][r * 128 + ((100 + d) ^ ((r & 7) << 3))] = f2bf(v);
        }
        if (lane < RPB) ts_lds[0][lane] = ts[(size_t)(rowbase + lane) * T_SZ + 0];
    }

    // per-lane cell assignment: 2 cells each.
    //   low lanes  (0-31):  rows 4G+0, 4G+1   (G = (lane>>4)&1)
    //   high lanes (32-63): rows 4G+2, 4G+3
    const bool lo = (lane < 32);
    const int  G  = (lane >> 4) & 1;
    const int  rA = 4 * G + (lo ? 0 : 2);
    const int  rB = rA + 1;
    const bool epi = (wave < 7) && (jj < H_SZ);
    // hoisted publish addresses: h -> row r, c -> row 8+r ((8+r)&7 == r&7)
    const int sjA = jj ^ ((rA & 7) << 3);
    const int sjB = jj ^ ((rB & 7) << 3);
    const int ixhA = rA * 128 + sjA,  ixcA = (8 + rA) * 128 + sjA;
    const int ixhB = rB * 128 + sjB,  ixcB = (8 + rB) * 128 + sjB;
    float cA = 0.f, cB = 0.f;          // f32 cell-state carries

    __syncthreads();

    int par = 0;
    for (int s = 0; s < T_SZ; ++s) {
        const unsigned short* hp = hx[par];

        if (wave < 7) {
            // single A-fragment set (h rows 0-7, c rows 8-15): 4 ds_read_b128
            bf16x8 a4[4];
            #pragma unroll
            for (int g = 0; g < 4; ++g) {
                const int idx = row16 * 128 + ((g * 32 + kgrp * 8) ^ ((row16 & 7) << 3));
                a4[g] = *(const bf16x8*)(hp + idx);
            }

            f32x4 acc[5];
            #pragma unroll
            for (int t = 0; t < 5; ++t) {
                f32x4 a = {0.f, 0.f, 0.f, 0.f};
                #pragma unroll
                for (int g = 0; g < 4; ++g)
                    a = __builtin_amdgcn_mfma_f32_16x16x32_bf16(a4[g], Bf[t][g], a, 0, 0, 0);
                acc[t] = a;
            }

            // exchange across the 32-lane halves:
            //   gate preacts e{2,3} go up (low -> high), decay e{0,1} come down
            const float s02 = __shfl_xor(acc[0][2], 32, 64);
            const float s12 = __shfl_xor(acc[1][2], 32, 64);
            const float s22 = __shfl_xor(acc[2][2], 32, 64);
            const float s32 = __shfl_xor(acc[3][2], 32, 64);
            const float s03 = __shfl_xor(acc[0][3], 32, 64);
            const float s13 = __shfl_xor(acc[1][3], 32, 64);
            const float s23 = __shfl_xor(acc[2][3], 32, 64);
            const float s33 = __shfl_xor(acc[3][3], 32, 64);
            const float sd0 = __shfl_xor(acc[4][0], 32, 64);
            const float sd1 = __shfl_xor(acc[4][1], 32, 64);

            if (epi) {
                const float fpA = lo ? acc[0][0] : s02;
                const float ipA = lo ? acc[1][0] : s12;
                const float opA = lo ? acc[2][0] : s22;
                const float gpA = lo ? acc[3][0] : s32;
                const float dpA = lo ? sd0       : acc[4][2];
                const float fpB = lo ? acc[0][1] : s03;
                const float ipB = lo ? acc[1][1] : s13;
                const float opB = lo ? acc[2][1] : s23;
                const float gpB = lo ? acc[3][1] : s33;
                const float dpB = lo ? sd1       : acc[4][3];

                unsigned short* hn = hx[par ^ 1];
                const float tsA = ts_lds[par][rA];
                const float tsB = ts_lds[par][rB];

                const float fA = sigm(fpA), iA = sigm(ipA), oA = sigm(opA), gA = sigm(gpA);
                const float csA = tanh_(dpA);
                cA = fA * (cA + csA * (tsA - 1.0f)) + iA * gA;
                const float hA = oA * tanh_(cA);

                const float fB = sigm(fpB), iB = sigm(ipB), oB = sigm(opB), gB = sigm(gpB);
                const float csB = tanh_(dpB);
                cB = fB * (cB + csB * (tsB - 1.0f)) + iB * gB;
                const float hB = oB * tanh_(cB);

                hn[ixhA] = f2bf(hA);  hn[ixcA] = f2bf(cA);
                hn[ixhB] = f2bf(hB);  hn[ixcB] = f2bf(cB);
                if (s == T_SZ - 1) { hl[rA][jj] = hA; hl[rB][jj] = hB; }
            }
        } else {
            // staging wave: x[s+1] (rows 0-7), ts[s+1] into the other parity
            const int s1 = (s + 1 < T_SZ) ? (s + 1) : s;
            #pragma unroll
            for (int q = 0; q < 3; ++q) {
                const int ii = lane * 3 + q;
                const int r = ii / 24, d = ii % 24;
                const float v = input_seq[((size_t)(rowbase + r) * T_SZ + s1) * D_SZ + d];
                hx[par ^ 1][r * 128 + ((100 + d) ^ ((r & 7) << 3))] = f2bf(v);
            }
            if (lane < RPB) ts_lds[par ^ 1][lane] = ts[(size_t)(rowbase + lane) * T_SZ + s1];
        }

        __syncthreads();   // single barrier per step (double-buffered state)
        par ^= 1;
    }

    // ---- output head: relu(h_last @ W_lin + b_lin), parallel reduce ----
    {
        const int rr = tid >> 6;        // 0..7 (one wave per row)
        const int o  = (tid >> 5) & 1;  // half-wave per output col
        const int k0 = tid & 31;
        float part = 0.f;
        for (int k = k0; k < H_SZ; k += 32)
            part += hl[rr][k] * W_lin[k * O_SZ + o];
        #pragma unroll
        for (int off = 16; off; off >>= 1)
            part += __shfl_xor(part, off, 64);
        if (k0 == 0)
            out[(size_t)(rowbase + rr) * O_SZ + o] = fmaxf(part + b_lin[o], 0.f);
    }
}

extern "C" void kernel_launch(void* const* d_in, const int* in_sizes, int n_in,
                              void* d_out, int out_size, void* d_ws, size_t ws_size,
                              hipStream_t stream) {
    const float* input_seq = (const float*)d_in[0];
    const float* ts_p      = (const float*)d_in[1];
    const float* W_all     = (const float*)d_in[2];
    const float* b_all     = (const float*)d_in[3];
    const float* U_all     = (const float*)d_in[4];
    const float* b_u       = (const float*)d_in[5];
    const float* W_d       = (const float*)d_in[6];
    const float* b_d       = (const float*)d_in[7];
    const float* W_lin     = (const float*)d_in[8];
    const float* b_lin     = (const float*)d_in[9];

    tlstm_kernel<<<dim3(B_SZ / RPB), dim3(512), 0, stream>>>(
        input_seq, ts_p, W_all, b_all, U_all, b_u, W_d, b_d, W_lin, b_lin,
        (float*)d_out);
}